// Round 10
// baseline (424.327 us; speedup 1.0000x reference)
//
#include <hip/hip_runtime.h>
#include <hip/hip_bf16.h>

#define H 64
#define F 128
#define G4 256   // 4*H
#define T 512
#define B 512
#define RB 16    // phase-1 batch rows per block
#define TC 8     // phase-1 time chunks per (dir,rowg)

typedef __attribute__((ext_vector_type(4))) float f32x4;
typedef __attribute__((ext_vector_type(8))) short bf16x8;

__device__ __forceinline__ short f2bf(float f) {
    union { float f; unsigned u; } v; v.f = f;
    unsigned r = (v.u + 0x7fffu + ((v.u >> 16) & 1u)) >> 16;
    return (short)r;
}
__device__ __forceinline__ short f2bf_cvt(float f) {
    unsigned r;
    asm("v_cvt_pk_bf16_f32 %0, %1, %1" : "=v"(r) : "v"(f));
    return (short)r;
}
__device__ __forceinline__ unsigned cvtpk(float lo, float hi) {
    unsigned r;
    asm("v_cvt_pk_bf16_f32 %0, %1, %2" : "=v"(r) : "v"(lo), "v"(hi));
    return r;
}
__device__ __forceinline__ float bf2f(short s) {
    union { unsigned u; float f; } v; v.u = ((unsigned)(unsigned short)s) << 16;
    return v.f;
}
__device__ __forceinline__ float bflo(unsigned u) {
    union { unsigned u; float f; } v; v.u = u << 16; return v.f;
}
__device__ __forceinline__ float bfhi(unsigned u) {
    union { unsigned u; float f; } v; v.u = u & 0xffff0000u; return v.f;
}
__device__ __forceinline__ float sigf(float x) {
    return __builtin_amdgcn_rcpf(1.f + __expf(-x));
}
__device__ __forceinline__ float tanhf_(float x) {
    float e = __expf(2.f * x);
    return 1.f - 2.f * __builtin_amdgcn_rcpf(e + 1.f);
}

// Load one timestep's x A-fragments (4 K-tiles of 32) for this lane.
#define LOADX(XR, TT) do {                                                     \
    int _b = (TT) * F + 4 * lq;                                                \
    _Pragma("unroll")                                                          \
    for (int kt = 0; kt < 4; ++kt) {                                           \
        XR[kt][0] = *(const f32x4*)(xlane + _b + 32 * kt);                     \
        XR[kt][1] = *(const f32x4*)(xlane + _b + 32 * kt + 16);                \
    }                                                                          \
} while (0)

// ---------------------------------------------------------------------------
// Phase 1: xp = bias + x.W (bf16).  Layout keyed to the rec kernel:
// tile = dir*128 + rowg*4 + lq (a 4-row tile), per pair (t/2) a 4KB record:
//   offset = w*1024 + (t&1)*512 + row*128 + unit_lo*8, 8B = 4 gates {i,f|g,o}
// so rec wave w stages/reads exactly its own 1KB slice per pair.
// Phase-1 thread (w,lr) holds all 4 gates of unit j = w*16+lr (s = gate).
// ---------------------------------------------------------------------------
#define XBODY(TCUR, XR) do {                                                   \
    bf16x8 af[4];                                                              \
    _Pragma("unroll")                                                          \
    for (int kt = 0; kt < 4; ++kt) {                                           \
        bf16x8 v;                                                              \
        _Pragma("unroll")                                                      \
        for (int e = 0; e < 4; ++e) {                                          \
            v[e]     = f2bf(XR[kt][0][e]);                                     \
            v[e + 4] = f2bf(XR[kt][1][e]);                                     \
        }                                                                      \
        af[kt] = v;                                                            \
    }                                                                          \
    {   int tn = (TCUR) + 2; if (tn > T - 1) tn = T - 1;                       \
        int ttn = dir ? (T - 1 - tn) : tn;                                     \
        LOADX(XR, ttn); }                                                      \
    f32x4 acc[4];                                                              \
    _Pragma("unroll")                                                          \
    for (int s = 0; s < 4; ++s)                                                \
        acc[s] = (f32x4){bsc[s], bsc[s], bsc[s], bsc[s]};                      \
    _Pragma("unroll")                                                          \
    for (int kt = 0; kt < 4; ++kt)                                             \
        _Pragma("unroll")                                                      \
        for (int s = 0; s < 4; ++s)                                            \
            acc[s] = __builtin_amdgcn_mfma_f32_16x16x32_bf16(                  \
                af[kt], wfr[kt][s], acc[s], 0, 0, 0);                          \
    {   size_t _base = ((size_t)(dir * 128 + rowg * 4 + lq) * (T / 2)          \
                        + ((TCUR) >> 1)) * 4096                                \
                       + w * 1024 + ((TCUR) & 1) * 512 + lr * 8;               \
        _Pragma("unroll")                                                      \
        for (int e = 0; e < 4; ++e) {                                          \
            uint2 pv;                                                          \
            pv.x = cvtpk(acc[0][e], acc[1][e]);                                \
            pv.y = cvtpk(acc[2][e], acc[3][e]);                                \
            *(uint2*)(xpb + _base + e * 128) = pv;                             \
        }                                                                      \
    }                                                                          \
} while (0)

__global__ __launch_bounds__(256, 1)
void xw_gemm(const float* __restrict__ x,
             const float* __restrict__ Wf, const float* __restrict__ bfv,
             const float* __restrict__ Wb, const float* __restrict__ bbv,
             char* __restrict__ xpb) {
    const int tid = threadIdx.x;
    const int l = tid & 63, w = tid >> 6;
    const int lq = l >> 4, lr = l & 15;
    const int dir  = blockIdx.x >> 8;
    const int rowg = (blockIdx.x >> 3) & 31;
    const int tc   = blockIdx.x & 7;
    const int r0 = rowg * RB;
    const int t0 = tc * (T / TC);

    const float* __restrict__ Wm = dir ? Wb : Wf;
    const float* __restrict__ bv = dir ? bbv : bfv;

    // wave w owns cols {g*64 + 16w + lr}: thread holds 4 gates of unit 16w+lr
    bf16x8 wfr[4][4];
#pragma unroll
    for (int kt = 0; kt < 4; ++kt)
#pragma unroll
        for (int s = 0; s < 4; ++s) {
            int col = s * 64 + 16 * w + lr;
            int k0 = kt * 32 + 4 * lq;
            bf16x8 v;
#pragma unroll
            for (int e = 0; e < 4; ++e) {
                v[e]     = f2bf(Wm[(k0 + e) * G4 + col]);
                v[e + 4] = f2bf(Wm[(k0 + 16 + e) * G4 + col]);
            }
            wfr[kt][s] = v;
        }
    float bsc[4];
#pragma unroll
    for (int s = 0; s < 4; ++s) bsc[s] = bv[s * 64 + 16 * w + lr];

    const float* xlane = x + (size_t)(r0 + lr) * (T * F);

    f32x4 xrA[4][2], xrB[4][2];
    { int tt0 = dir ? (T - 1 - t0) : t0;       LOADX(xrA, tt0); }
    { int tt1 = dir ? (T - 2 - t0) : (t0 + 1); LOADX(xrB, tt1); }

    for (int t = t0; t < t0 + T / TC; t += 2) {
        XBODY(t,     xrA);
        XBODY(t + 1, xrB);
    }
}

// ---------------------------------------------------------------------------
// Phase 2: recurrence, 4 rows/block, 256 blocks.  Wave w owns all 4 gates of
// units 16w..16w+15, so the z exchange is WAVE-LOCAL (lgkmcnt-only, no
// barrier).  ONE block barrier per step (cross-wave h A-fragment exchange).
// xp staged 4 pairs deep via global_load_lds, wave-local vmcnt(3) ordering.
// ---------------------------------------------------------------------------
#define STAGE(PAIR, BUF) do {                                                  \
    int _p = (PAIR); if (_p > T / 2 - 1) _p = T / 2 - 1;                       \
    const char* _g = (const char*)xpc + (size_t)_p * 4096 + w * 1024 + 16 * l; \
    char* _lb = xps + (BUF) * 4096 + w * 1024;                                 \
    __builtin_amdgcn_global_load_lds(                                          \
        (const __attribute__((address_space(1))) void*)_g,                     \
        (__attribute__((address_space(3))) void*)_lb, 16, 0, 0);               \
} while (0)

#define RSTEP(TCUR, BUF, PRD, PWR, DOSTAGE) do {                               \
    bf16x8 hf0 = *(const bf16x8*)(hlds + (PRD) * 2048 + rd_off);               \
    bf16x8 hf1 = *(const bf16x8*)(hlds + (PRD) * 2048 + 1024 + rd_off);        \
    f32x4 acc[4];                                                              \
    _Pragma("unroll")                                                          \
    for (int s = 0; s < 4; ++s) acc[s] = (f32x4){0.f, 0.f, 0.f, 0.f};          \
    _Pragma("unroll")                                                          \
    for (int s = 0; s < 4; ++s)                                                \
        acc[s] = __builtin_amdgcn_mfma_f32_16x16x32_bf16(                      \
            hf0, ufr[0][s], acc[s], 0, 0, 0);                                  \
    _Pragma("unroll")                                                          \
    for (int s = 0; s < 4; ++s)                                                \
        acc[s] = __builtin_amdgcn_mfma_f32_16x16x32_bf16(                      \
            hf1, ufr[1][s], acc[s], 0, 0, 0);                                  \
    if (lq == 0) {                                                             \
        _Pragma("unroll")                                                      \
        for (int e = 0; e < 4; ++e) {                                          \
            f32x4 zw = {acc[0][e], acc[1][e], acc[2][e], acc[3][e]};           \
            *(f32x4*)(zbc + w * 1024 + e * 256 + lr * 16) = zw;                \
        }                                                                      \
    }                                                                          \
    asm volatile("s_waitcnt lgkmcnt(0)" ::: "memory");                         \
    asm volatile("s_waitcnt vmcnt(3)" ::: "memory");                           \
    __builtin_amdgcn_sched_barrier(0);                                         \
    f32x4 zv = *(const f32x4*)(zbc + w * 1024 + (l >> 4) * 256 + (l & 15) * 16); \
    uint2 xv = *(const uint2*)(xps + (BUF) * 4096 + w * 1024                   \
                               + ((TCUR) & 1) * 512 + (l >> 4) * 128           \
                               + (l & 15) * 8);                                \
    float zi = zv[0] + bflo(xv.x);                                             \
    float zf = zv[1] + bfhi(xv.x);                                             \
    float zg = zv[2] + bflo(xv.y);                                             \
    float zo = zv[3] + bfhi(xv.y);                                             \
    float ei = __expf(-zi);                                                    \
    float ef = __expf(-zf);                                                    \
    float eg = __expf(2.f * fminf(zg, 15.f));                                  \
    float sf = __builtin_amdgcn_rcpf(1.f + ef);                                \
    float dig = __builtin_amdgcn_rcpf((1.f + ei) * (1.f + eg));                \
    cc = fmaf(sf, cc, (eg - 1.f) * dig);                                       \
    float eo = __expf(-zo);                                                    \
    float ec = __expf(2.f * fminf(cc, 15.f));                                  \
    float doc = __builtin_amdgcn_rcpf((1.f + eo) * (1.f + ec));                \
    hh = (ec - 1.f) * doc;                                                     \
    *(short*)(hlds + (PWR) * 2048 + wr) = f2bf_cvt(hh);                        \
    asm volatile("s_waitcnt lgkmcnt(0)" ::: "memory");                         \
    if (DOSTAGE) { STAGE(((TCUR) >> 1) + 4, BUF); }                            \
    __builtin_amdgcn_sched_barrier(0);                                         \
    __builtin_amdgcn_s_barrier();                                              \
    __builtin_amdgcn_sched_barrier(0);                                         \
} while (0)

__global__ __launch_bounds__(256, 1)
void lstm_rec(const char* __restrict__ xpb,
              const float* __restrict__ Uf, const float* __restrict__ Ub,
              float* __restrict__ hcat /* [B][2H] */) {
    const int tid = threadIdx.x;
    const int l = tid & 63, w = tid >> 6;
    const int lq = l >> 4, lr = l & 15;
    const int dir = blockIdx.x >> 7;
    const int rowg = blockIdx.x & 127;   // 4-row tile index
    const int r0 = rowg * 4;

    const float* __restrict__ Um = dir ? Ub : Uf;

    // wave w owns all 4 gates of units 16w..16w+15
    bf16x8 ufr[2][4];
#pragma unroll
    for (int kt = 0; kt < 2; ++kt)
#pragma unroll
        for (int s = 0; s < 4; ++s) {
            int col = s * 64 + 16 * w + lr;
            int k0 = kt * 32 + 4 * lq;
            bf16x8 v;
#pragma unroll
            for (int e = 0; e < 4; ++e) {
                v[e]     = f2bf(Um[(k0 + e) * G4 + col]);
                v[e + 4] = f2bf(Um[(k0 + 16 + e) * G4 + col]);
            }
            ufr[kt][s] = v;
        }

    __shared__ __align__(16) char xps[4 * 4096];   // 4 pair-bufs
    __shared__ __align__(16) char hlds[4096];      // h A-frag double buffer
    __shared__ __align__(16) char zbc[4096];       // wave-private z exchange

    ((f32x4*)hlds)[tid] = (f32x4){0.f, 0.f, 0.f, 0.f};
    __syncthreads();

    const int rd_off = (l * 16) ^ (((l >> 4) & 3) << 4);

    // gate thread owns (row = l>>4, unit j = 16w + (l&15)); h-frag write offset
    int wr;
    {
        int j = 16 * w + (l & 15);
        int fl = (l >> 4) + 16 * ((j >> 2) & 3);
        wr = (j >> 5) * 1024 + ((fl * 16) ^ (((fl >> 4) & 3) << 4))
             + ((j & 3) + 4 * ((j >> 4) & 1)) * 2;
    }

    const char* xpc = xpb + (size_t)(dir * 128 + rowg) * (T / 2) * 4096;

    // prologue: stage pairs 0..3 (4 loads/wave in flight)
    STAGE(0, 0);
    STAGE(1, 1);
    STAGE(2, 2);
    STAGE(3, 3);

    float cc = 0.f, hh = 0.f;

    for (int t = 0; t < T; t += 8) {
        RSTEP(t + 0, 0, 0, 1, 0);
        RSTEP(t + 1, 0, 1, 0, 1);
        RSTEP(t + 2, 1, 0, 1, 0);
        RSTEP(t + 3, 1, 1, 0, 1);
        RSTEP(t + 4, 2, 0, 1, 0);
        RSTEP(t + 5, 2, 1, 0, 1);
        RSTEP(t + 6, 3, 0, 1, 0);
        RSTEP(t + 7, 3, 1, 0, 1);
    }

    // final hidden state: thread owns (row = l>>4, unit = 16w + (l&15))
    hcat[(size_t)(r0 + (l >> 4)) * (2 * H) + dir * H + 16 * w + (l & 15)] = hh;
}

// ---------------------------------------------------------------------------
// Fallback fused kernel (verified round-2 path) if ws is too small for xp.
// ---------------------------------------------------------------------------
#define BODY(TCUR, XR, PRD, PWR) do {                                          \
    bf16x8 af[4];                                                              \
    _Pragma("unroll")                                                          \
    for (int kt = 0; kt < 4; ++kt) {                                           \
        bf16x8 v;                                                              \
        _Pragma("unroll")                                                      \
        for (int e = 0; e < 4; ++e) {                                          \
            v[e]     = f2bf(XR[kt][0][e]);                                     \
            v[e + 4] = f2bf(XR[kt][1][e]);                                     \
        }                                                                      \
        af[kt] = v;                                                            \
    }                                                                          \
    {   int tn = (TCUR) + 2; if (tn > T - 1) tn = T - 1;                       \
        int ttn = dir ? (T - 1 - tn) : tn;                                     \
        LOADX(XR, ttn); }                                                      \
    bf16x8 hf0 = *(const bf16x8*)(hlds + (PRD) * 2048 + rd_off);               \
    bf16x8 hf1 = *(const bf16x8*)(hlds + (PRD) * 2048 + 1024 + rd_off);        \
    f32x4 acc[4];                                                              \
    _Pragma("unroll")                                                          \
    for (int s = 0; s < 4; ++s)                                                \
        acc[s] = (f32x4){bsc[s], bsc[s], bsc[s], bsc[s]};                      \
    _Pragma("unroll")                                                          \
    for (int kt = 0; kt < 4; ++kt)                                             \
        _Pragma("unroll")                                                      \
        for (int s = 0; s < 4; ++s)                                            \
            acc[s] = __builtin_amdgcn_mfma_f32_16x16x32_bf16(                  \
                af[kt], wfr[kt][s], acc[s], 0, 0, 0);                          \
    _Pragma("unroll")                                                          \
    for (int s = 0; s < 4; ++s)                                                \
        acc[s] = __builtin_amdgcn_mfma_f32_16x16x32_bf16(                      \
            hf0, ufr[0][s], acc[s], 0, 0, 0);                                  \
    _Pragma("unroll")                                                          \
    for (int s = 0; s < 4; ++s)                                                \
        acc[s] = __builtin_amdgcn_mfma_f32_16x16x32_bf16(                      \
            hf1, ufr[1][s], acc[s], 0, 0, 0);                                  \
    _Pragma("unroll")                                                          \
    for (int e = 0; e < 4; ++e) {                                              \
        float ig = sigf(acc[0][e]);                                            \
        float fg = sigf(acc[1][e]);                                            \
        float gg = tanhf_(acc[2][e]);                                          \
        float og = sigf(acc[3][e]);                                            \
        c4[e] = fmaf(fg, c4[e], ig * gg);                                      \
        hq[e] = og * tanhf_(c4[e]);                                            \
        *(short*)(hlds + (PWR) * 2048 + wr_off[e]) = f2bf(hq[e]);              \
    }                                                                          \
    __syncthreads();                                                           \
} while (0)

__global__ __launch_bounds__(256, 1)
void lstm_mfma(const float* __restrict__ x,
               const float* __restrict__ Wf, const float* __restrict__ Uf,
               const float* __restrict__ bfv,
               const float* __restrict__ Wb, const float* __restrict__ Ub,
               const float* __restrict__ bbv,
               float* __restrict__ hcat) {
    const int tid = threadIdx.x;
    const int l = tid & 63, w = tid >> 6;
    const int lq = l >> 4, lr = l & 15;
    const int dir = blockIdx.x >> 5;
    const int r0 = (blockIdx.x & 31) * RB;

    const float* __restrict__ Wm = dir ? Wb : Wf;
    const float* __restrict__ Um = dir ? Ub : Uf;
    const float* __restrict__ bv = dir ? bbv : bfv;

    bf16x8 wfr[4][4];
#pragma unroll
    for (int kt = 0; kt < 4; ++kt)
#pragma unroll
        for (int s = 0; s < 4; ++s) {
            int col = (w + 4 * s) * 16 + lr;
            int k0 = kt * 32 + 4 * lq;
            bf16x8 v;
#pragma unroll
            for (int e = 0; e < 4; ++e) {
                v[e]     = f2bf(Wm[(k0 + e) * G4 + col]);
                v[e + 4] = f2bf(Wm[(k0 + 16 + e) * G4 + col]);
            }
            wfr[kt][s] = v;
        }
    bf16x8 ufr[2][4];
#pragma unroll
    for (int kt = 0; kt < 2; ++kt)
#pragma unroll
        for (int s = 0; s < 4; ++s) {
            int col = (w + 4 * s) * 16 + lr;
            int k0 = kt * 32 + 4 * lq;
            bf16x8 v;
#pragma unroll
            for (int e = 0; e < 4; ++e) {
                v[e]     = f2bf(Um[(k0 + e) * G4 + col]);
                v[e + 4] = f2bf(Um[(k0 + 16 + e) * G4 + col]);
            }
            ufr[kt][s] = v;
        }
    float bsc[4];
#pragma unroll
    for (int s = 0; s < 4; ++s) bsc[s] = bv[(w + 4 * s) * 16 + lr];

    __shared__ __align__(16) char hlds[4096];
    ((f32x4*)hlds)[tid] = (f32x4){0.f, 0.f, 0.f, 0.f};
    __syncthreads();

    const int rd_off = (l * 16) ^ (((l >> 4) & 3) << 4);
    const int j = 16 * w + lr;
    const int kt_j = j >> 5;
    const int elem_j = (j & 3) + 4 * ((j >> 4) & 1);
    int wr_off[4];
#pragma unroll
    for (int e = 0; e < 4; ++e) {
        int fl = 4 * lq + e + 16 * ((j >> 2) & 3);
        wr_off[e] = kt_j * 1024 + ((fl * 16) ^ (((fl >> 4) & 3) << 4)) + elem_j * 2;
    }

    const float* xlane = x + (size_t)(r0 + lr) * (T * F);

    f32x4 xrA[4][2], xrB[4][2];
    { int tt0 = dir ? (T - 1) : 0; LOADX(xrA, tt0); }
    { int tt1 = dir ? (T - 2) : 1; LOADX(xrB, tt1); }

    float c4[4] = {0.f, 0.f, 0.f, 0.f};
    float hq[4] = {0.f, 0.f, 0.f, 0.f};

    for (int t = 0; t < T; t += 2) {
        BODY(t,     xrA, 0, 1);
        BODY(t + 1, xrB, 1, 0);
    }

#pragma unroll
    for (int e = 0; e < 4; ++e) {
        int row = 4 * lq + e;
        hcat[(size_t)(r0 + row) * (2 * H) + dir * H + j] = hq[e];
    }
}

// out[b][e] = relu(sum_k hcat[b][k] * Wd[k][e] + bd[e])   (fp32)
__global__ void dense_kernel(const float* __restrict__ hcat,
                             const float* __restrict__ Wd,
                             const float* __restrict__ bd,
                             float* __restrict__ out) {
    const int b = blockIdx.x;
    const int e = threadIdx.x;   // 128 threads
    float acc = bd[e];
#pragma unroll
    for (int k = 0; k < 2 * H; ++k)
        acc = fmaf(hcat[b * (2 * H) + k], Wd[k * 128 + e], acc);
    out[b * 128 + e] = fmaxf(acc, 0.f);
}

extern "C" void kernel_launch(void* const* d_in, const int* in_sizes, int n_in,
                              void* d_out, int out_size, void* d_ws, size_t ws_size,
                              hipStream_t stream) {
    const float* x       = (const float*)d_in[0];
    const float* W_fwd   = (const float*)d_in[1];
    const float* U_fwd   = (const float*)d_in[2];
    const float* b_fwd   = (const float*)d_in[3];
    const float* W_bwd   = (const float*)d_in[4];
    const float* U_bwd   = (const float*)d_in[5];
    const float* b_bwd   = (const float*)d_in[6];
    const float* W_dense = (const float*)d_in[7];
    const float* b_dense = (const float*)d_in[8];
    float* out = (float*)d_out;

    // xp: 256 tiles x (T/2 pairs) x 4096 B = 256 MB
    const size_t XP_BYTES = (size_t)256 * (T / 2) * 4096;
    const size_t HCAT_BYTES = (size_t)B * 2 * H * 4;

    if (ws_size >= XP_BYTES + HCAT_BYTES) {
        char*  xpb  = (char*)d_ws;
        float* hcat = (float*)((char*)d_ws + XP_BYTES);

        xw_gemm<<<dim3(2 * 32 * TC), dim3(256), 0, stream>>>(
            x, W_fwd, b_fwd, W_bwd, b_bwd, xpb);
        lstm_rec<<<dim3(256), dim3(256), 0, stream>>>(
            xpb, U_fwd, U_bwd, hcat);
        dense_kernel<<<dim3(B), dim3(128), 0, stream>>>(hcat, W_dense, b_dense, out);
    } else {
        float* hcat = (float*)d_ws;
        lstm_mfma<<<dim3(2 * (B / RB)), dim3(256), 0, stream>>>(
            x, W_fwd, U_fwd, b_fwd, W_bwd, U_bwd, b_bwd, hcat);
        dense_kernel<<<dim3(B), dim3(128), 0, stream>>>(hcat, W_dense, b_dense, out);
    }
}

// Round 11
// 319.368 us; speedup vs baseline: 1.3286x; 1.3286x over previous
//
#include <hip/hip_runtime.h>
#include <hip/hip_bf16.h>

#define H 64
#define F 128
#define G4 256   // 4*H
#define T 512
#define B 512
#define RB 16    // phase-1 batch rows per block
#define TC 8     // phase-1 time chunks per rowg

typedef __attribute__((ext_vector_type(4))) float f32x4;
typedef __attribute__((ext_vector_type(8))) short bf16x8;

__device__ __forceinline__ short f2bf(float f) {
    union { float f; unsigned u; } v; v.f = f;
    unsigned r = (v.u + 0x7fffu + ((v.u >> 16) & 1u)) >> 16;
    return (short)r;
}
__device__ __forceinline__ short f2bf_cvt(float f) {
    unsigned r;
    asm("v_cvt_pk_bf16_f32 %0, %1, %1" : "=v"(r) : "v"(f));
    return (short)r;
}
__device__ __forceinline__ unsigned cvtpk(float lo, float hi) {
    unsigned r;
    asm("v_cvt_pk_bf16_f32 %0, %1, %2" : "=v"(r) : "v"(lo), "v"(hi));
    return r;
}
__device__ __forceinline__ float bf2f(short s) {
    union { unsigned u; float f; } v; v.u = ((unsigned)(unsigned short)s) << 16;
    return v.f;
}
__device__ __forceinline__ float bflo(unsigned u) {
    union { unsigned u; float f; } v; v.u = u << 16; return v.f;
}
__device__ __forceinline__ float bfhi(unsigned u) {
    union { unsigned u; float f; } v; v.u = u & 0xffff0000u; return v.f;
}
__device__ __forceinline__ float sigf(float x) {
    return __builtin_amdgcn_rcpf(1.f + __expf(-x));
}
__device__ __forceinline__ float tanhf_(float x) {
    float e = __expf(2.f * x);
    return 1.f - 2.f * __builtin_amdgcn_rcpf(e + 1.f);
}

// Load one timestep's x A-fragments (4 K-tiles of 32) for this lane.
#define LOADX(XR, TT) do {                                                     \
    int _b = (TT) * F + 4 * lq;                                                \
    _Pragma("unroll")                                                          \
    for (int kt = 0; kt < 4; ++kt) {                                           \
        XR[kt][0] = *(const f32x4*)(xlane + _b + 32 * kt);                     \
        XR[kt][1] = *(const f32x4*)(xlane + _b + 32 * kt + 16);                \
    }                                                                          \
} while (0)

// ---------------------------------------------------------------------------
// Phase 1 (dual-direction): ONE read of x[row][tt] produces BOTH
// xp_fwd(slot tt) and xp_bwd(slot T-1-tt).  Layout (keyed to lstm_rec):
// tile = dir*128 + rowg*4 + lq; per pair a 4KB record:
//   row*1024 + (slot&1)*512 + unit*8, 8B = 4 bf16 gates {i,f | g,o}.
// ---------------------------------------------------------------------------
#define STOREXP(DIRBASE, SLOT, ACC) do {                                       \
    size_t _base = ((size_t)((DIRBASE) + rowg * 4 + lq) * (T / 2)              \
                    + ((SLOT) >> 1)) * 4096                                    \
                   + ((SLOT) & 1) * 512 + (16 * w + lr) * 8;                   \
    _Pragma("unroll")                                                          \
    for (int e = 0; e < 4; ++e) {                                              \
        uint2 pv;                                                              \
        pv.x = cvtpk(ACC[0][e], ACC[1][e]);                                    \
        pv.y = cvtpk(ACC[2][e], ACC[3][e]);                                    \
        *(uint2*)(xpb + _base + e * 1024) = pv;                                \
    }                                                                          \
} while (0)

#define XBODY2(TCUR, XR) do {                                                  \
    bf16x8 af[4];                                                              \
    _Pragma("unroll")                                                          \
    for (int kt = 0; kt < 4; ++kt) {                                           \
        bf16x8 v;                                                              \
        _Pragma("unroll")                                                      \
        for (int e = 0; e < 4; ++e) {                                          \
            v[e]     = f2bf(XR[kt][0][e]);                                     \
            v[e + 4] = f2bf(XR[kt][1][e]);                                     \
        }                                                                      \
        af[kt] = v;                                                            \
    }                                                                          \
    {   int tn = (TCUR) + 2; if (tn > T - 1) tn = T - 1;                       \
        LOADX(XR, tn); }                                                       \
    {   f32x4 accf[4];                                                         \
        _Pragma("unroll")                                                      \
        for (int s = 0; s < 4; ++s)                                            \
            accf[s] = (f32x4){bscf[s], bscf[s], bscf[s], bscf[s]};             \
        _Pragma("unroll")                                                      \
        for (int kt = 0; kt < 4; ++kt)                                         \
            _Pragma("unroll")                                                  \
            for (int s = 0; s < 4; ++s)                                        \
                accf[s] = __builtin_amdgcn_mfma_f32_16x16x32_bf16(             \
                    af[kt], wff[kt][s], accf[s], 0, 0, 0);                     \
        STOREXP(0, (TCUR), accf);                                              \
    }                                                                          \
    {   f32x4 accb[4];                                                         \
        _Pragma("unroll")                                                      \
        for (int s = 0; s < 4; ++s)                                            \
            accb[s] = (f32x4){bscb[s], bscb[s], bscb[s], bscb[s]};             \
        _Pragma("unroll")                                                      \
        for (int kt = 0; kt < 4; ++kt)                                         \
            _Pragma("unroll")                                                  \
            for (int s = 0; s < 4; ++s)                                        \
                accb[s] = __builtin_amdgcn_mfma_f32_16x16x32_bf16(             \
                    af[kt], wfb[kt][s], accb[s], 0, 0, 0);                     \
        STOREXP(128, T - 1 - (TCUR), accb);                                    \
    }                                                                          \
} while (0)

__global__ __launch_bounds__(256, 1)
void xw_gemm(const float* __restrict__ x,
             const float* __restrict__ Wf, const float* __restrict__ bfv,
             const float* __restrict__ Wb, const float* __restrict__ bbv,
             char* __restrict__ xpb) {
    const int tid = threadIdx.x;
    const int l = tid & 63, w = tid >> 6;
    const int lq = l >> 4, lr = l & 15;
    const int rowg = blockIdx.x >> 3;   // 32 row groups of 16
    const int tc   = blockIdx.x & 7;
    const int r0 = rowg * RB;
    const int t0 = tc * (T / TC);

    // wave w owns N-families {w, w+4, w+8, w+12}: acc[s] = gate s of unit 16w+lr
    bf16x8 wff[4][4], wfb[4][4];
#pragma unroll
    for (int kt = 0; kt < 4; ++kt)
#pragma unroll
        for (int s = 0; s < 4; ++s) {
            int col = (w + 4 * s) * 16 + lr;
            int k0 = kt * 32 + 4 * lq;
            bf16x8 vf, vb;
#pragma unroll
            for (int e = 0; e < 4; ++e) {
                vf[e]     = f2bf(Wf[(k0 + e) * G4 + col]);
                vf[e + 4] = f2bf(Wf[(k0 + 16 + e) * G4 + col]);
                vb[e]     = f2bf(Wb[(k0 + e) * G4 + col]);
                vb[e + 4] = f2bf(Wb[(k0 + 16 + e) * G4 + col]);
            }
            wff[kt][s] = vf;
            wfb[kt][s] = vb;
        }
    float bscf[4], bscb[4];
#pragma unroll
    for (int s = 0; s < 4; ++s) {
        bscf[s] = bfv[(w + 4 * s) * 16 + lr];
        bscb[s] = bbv[(w + 4 * s) * 16 + lr];
    }

    const float* xlane = x + (size_t)(r0 + lr) * (T * F);

    f32x4 xrA[4][2], xrB[4][2];
    LOADX(xrA, t0);
    LOADX(xrB, t0 + 1);

    for (int t = t0; t < t0 + T / TC; t += 2) {
        XBODY2(t,     xrA);
        XBODY2(t + 1, xrB);
    }
}

// ---------------------------------------------------------------------------
// Phase 2: recurrence (verified R9 structure: 4 rows/block, 256 blocks).
// Per step: 8 MFMAs (lanes 0-15 hold C) -> LDS z-exchange (barrier) ->
// all 256 threads gate ONE unit each (8 trans) -> h-frag write -> barrier.
// xp staged 4 pairs deep via global_load_lds, wave-local vmcnt(3) ordering.
// ---------------------------------------------------------------------------
#define STAGE(PAIR, BUF) do {                                                  \
    int _p = (PAIR); if (_p > T / 2 - 1) _p = T / 2 - 1;                       \
    const char* _g = (const char*)xpc + ((size_t)_p * 4 + w) * 1024 + 16 * l;  \
    char* _lb = xps + (BUF) * 4096 + w * 1024;                                 \
    __builtin_amdgcn_global_load_lds(                                          \
        (const __attribute__((address_space(1))) void*)_g,                     \
        (__attribute__((address_space(3))) void*)_lb, 16, 0, 0);               \
} while (0)

#define RSTEP(TCUR, BUF, PRD, PWR, DOSTAGE) do {                               \
    bf16x8 hf0 = *(const bf16x8*)(hlds + (PRD) * 2048 + rd_off);               \
    bf16x8 hf1 = *(const bf16x8*)(hlds + (PRD) * 2048 + 1024 + rd_off);        \
    f32x4 acc[4];                                                              \
    _Pragma("unroll")                                                          \
    for (int s = 0; s < 4; ++s) acc[s] = (f32x4){0.f, 0.f, 0.f, 0.f};          \
    _Pragma("unroll")                                                          \
    for (int s = 0; s < 4; ++s)                                                \
        acc[s] = __builtin_amdgcn_mfma_f32_16x16x32_bf16(                      \
            hf0, ufr[0][s], acc[s], 0, 0, 0);                                  \
    _Pragma("unroll")                                                          \
    for (int s = 0; s < 4; ++s)                                                \
        acc[s] = __builtin_amdgcn_mfma_f32_16x16x32_bf16(                      \
            hf1, ufr[1][s], acc[s], 0, 0, 0);                                  \
    if (lq == 0) {                                                             \
        _Pragma("unroll")                                                      \
        for (int e = 0; e < 4; ++e) {                                          \
            f32x4 zw = {acc[0][e], acc[1][e], acc[2][e], acc[3][e]};           \
            *(f32x4*)(zbc + e * 1024 + w * 256 + lr * 16) = zw;                \
        }                                                                      \
    }                                                                          \
    asm volatile("s_waitcnt lgkmcnt(0)" ::: "memory");                         \
    __builtin_amdgcn_s_barrier();                                              \
    asm volatile("s_waitcnt vmcnt(3)" ::: "memory");                           \
    __builtin_amdgcn_sched_barrier(0);                                         \
    f32x4 zv = *(const f32x4*)(zbc + tid * 16);                                \
    uint2 xv = *(const uint2*)(xps + (BUF) * 4096 + w * 1024                   \
                               + ((TCUR) & 1) * 512 + l * 8);                  \
    float zi = zv[0] + bflo(xv.x);                                             \
    float zf = zv[1] + bfhi(xv.x);                                             \
    float zg = zv[2] + bflo(xv.y);                                             \
    float zo = zv[3] + bfhi(xv.y);                                             \
    float ei = __expf(-zi);                                                    \
    float ef = __expf(-zf);                                                    \
    float eg = __expf(2.f * fminf(zg, 15.f));                                  \
    float sf = __builtin_amdgcn_rcpf(1.f + ef);                                \
    float dig = __builtin_amdgcn_rcpf((1.f + ei) * (1.f + eg));                \
    cc = fmaf(sf, cc, (eg - 1.f) * dig);                                       \
    float eo = __expf(-zo);                                                    \
    float ec = __expf(2.f * fminf(cc, 15.f));                                  \
    float doc = __builtin_amdgcn_rcpf((1.f + eo) * (1.f + ec));                \
    hh = (ec - 1.f) * doc;                                                     \
    *(short*)(hlds + (PWR) * 2048 + wr) = f2bf_cvt(hh);                        \
    asm volatile("s_waitcnt lgkmcnt(0)" ::: "memory");                         \
    if (DOSTAGE) { STAGE(((TCUR) >> 1) + 4, BUF); }                            \
    __builtin_amdgcn_sched_barrier(0);                                         \
    __builtin_amdgcn_s_barrier();                                              \
    __builtin_amdgcn_sched_barrier(0);                                         \
} while (0)

__global__ __launch_bounds__(256, 1)
void lstm_rec(const char* __restrict__ xpb,
              const float* __restrict__ Uf, const float* __restrict__ Ub,
              float* __restrict__ hcat /* [B][2H] */) {
    const int tid = threadIdx.x;
    const int l = tid & 63, w = tid >> 6;
    const int lq = l >> 4, lr = l & 15;
    const int dir = blockIdx.x >> 7;
    const int rowg = blockIdx.x & 127;   // 4-row tile index
    const int r0 = rowg * 4;

    const float* __restrict__ Um = dir ? Ub : Uf;

    bf16x8 ufr[2][4];
#pragma unroll
    for (int kt = 0; kt < 2; ++kt)
#pragma unroll
        for (int s = 0; s < 4; ++s) {
            int col = (w + 4 * s) * 16 + lr;
            int k0 = kt * 32 + 4 * lq;
            bf16x8 v;
#pragma unroll
            for (int e = 0; e < 4; ++e) {
                v[e]     = f2bf(Um[(k0 + e) * G4 + col]);
                v[e + 4] = f2bf(Um[(k0 + 16 + e) * G4 + col]);
            }
            ufr[kt][s] = v;
        }

    __shared__ __align__(16) char xps[4 * 4096];   // 4 pair-bufs
    __shared__ __align__(16) char hlds[4096];      // h A-frag double buffer
    __shared__ __align__(16) char zbc[4096];       // z exchange [r][j][4 gates]

    ((f32x4*)hlds)[tid] = (f32x4){0.f, 0.f, 0.f, 0.f};
    __syncthreads();

    const int rd_off = (l * 16) ^ (((l >> 4) & 3) << 4);

    // gate thread owns unit (row = w, j = l); h-frag write offset for it
    const int gj = l;
    int wr;
    {
        int fl = w + 16 * ((gj >> 2) & 3);
        wr = (gj >> 5) * 1024 + ((fl * 16) ^ (((fl >> 4) & 3) << 4))
             + ((gj & 3) + 4 * ((gj >> 4) & 1)) * 2;
    }

    const char* xpc = xpb + (size_t)(dir * 128 + rowg) * (T / 2) * 4096;

    // prologue: stage pairs 0..3 (4 loads/wave in flight)
    STAGE(0, 0);
    STAGE(1, 1);
    STAGE(2, 2);
    STAGE(3, 3);

    float cc = 0.f, hh = 0.f;

    for (int t = 0; t < T; t += 8) {
        RSTEP(t + 0, 0, 0, 1, 0);
        RSTEP(t + 1, 0, 1, 0, 1);
        RSTEP(t + 2, 1, 0, 1, 0);
        RSTEP(t + 3, 1, 1, 0, 1);
        RSTEP(t + 4, 2, 0, 1, 0);
        RSTEP(t + 5, 2, 1, 0, 1);
        RSTEP(t + 6, 3, 0, 1, 0);
        RSTEP(t + 7, 3, 1, 0, 1);
    }

    // final hidden state: thread owns (row = w, unit = l)
    hcat[(size_t)(r0 + w) * (2 * H) + dir * H + l] = hh;
}

// ---------------------------------------------------------------------------
// Fallback fused kernel (verified round-2 path) if ws is too small for xp.
// ---------------------------------------------------------------------------
#define BODY(TCUR, XR, PRD, PWR) do {                                          \
    bf16x8 af[4];                                                              \
    _Pragma("unroll")                                                          \
    for (int kt = 0; kt < 4; ++kt) {                                           \
        bf16x8 v;                                                              \
        _Pragma("unroll")                                                      \
        for (int e = 0; e < 4; ++e) {                                          \
            v[e]     = f2bf(XR[kt][0][e]);                                     \
            v[e + 4] = f2bf(XR[kt][1][e]);                                     \
        }                                                                      \
        af[kt] = v;                                                            \
    }                                                                          \
    {   int tn = (TCUR) + 2; if (tn > T - 1) tn = T - 1;                       \
        int ttn = dir ? (T - 1 - tn) : tn;                                     \
        LOADX(XR, ttn); }                                                      \
    bf16x8 hf0 = *(const bf16x8*)(hlds + (PRD) * 2048 + rd_off);               \
    bf16x8 hf1 = *(const bf16x8*)(hlds + (PRD) * 2048 + 1024 + rd_off);        \
    f32x4 acc[4];                                                              \
    _Pragma("unroll")                                                          \
    for (int s = 0; s < 4; ++s)                                                \
        acc[s] = (f32x4){bsc[s], bsc[s], bsc[s], bsc[s]};                      \
    _Pragma("unroll")                                                          \
    for (int kt = 0; kt < 4; ++kt)                                             \
        _Pragma("unroll")                                                      \
        for (int s = 0; s < 4; ++s)                                            \
            acc[s] = __builtin_amdgcn_mfma_f32_16x16x32_bf16(                  \
                af[kt], wfr[kt][s], acc[s], 0, 0, 0);                          \
    _Pragma("unroll")                                                          \
    for (int s = 0; s < 4; ++s)                                                \
        acc[s] = __builtin_amdgcn_mfma_f32_16x16x32_bf16(                      \
            hf0, ufr[0][s], acc[s], 0, 0, 0);                                  \
    _Pragma("unroll")                                                          \
    for (int s = 0; s < 4; ++s)                                                \
        acc[s] = __builtin_amdgcn_mfma_f32_16x16x32_bf16(                      \
            hf1, ufr[1][s], acc[s], 0, 0, 0);                                  \
    _Pragma("unroll")                                                          \
    for (int e = 0; e < 4; ++e) {                                              \
        float ig = sigf(acc[0][e]);                                            \
        float fg = sigf(acc[1][e]);                                            \
        float gg = tanhf_(acc[2][e]);                                          \
        float og = sigf(acc[3][e]);                                            \
        c4[e] = fmaf(fg, c4[e], ig * gg);                                      \
        hq[e] = og * tanhf_(c4[e]);                                            \
        *(short*)(hlds + (PWR) * 2048 + wr_off[e]) = f2bf(hq[e]);              \
    }                                                                          \
    __syncthreads();                                                           \
} while (0)

__global__ __launch_bounds__(256, 1)
void lstm_mfma(const float* __restrict__ x,
               const float* __restrict__ Wf, const float* __restrict__ Uf,
               const float* __restrict__ bfv,
               const float* __restrict__ Wb, const float* __restrict__ Ub,
               const float* __restrict__ bbv,
               float* __restrict__ hcat) {
    const int tid = threadIdx.x;
    const int l = tid & 63, w = tid >> 6;
    const int lq = l >> 4, lr = l & 15;
    const int dir = blockIdx.x >> 5;
    const int r0 = (blockIdx.x & 31) * RB;

    const float* __restrict__ Wm = dir ? Wb : Wf;
    const float* __restrict__ Um = dir ? Ub : Uf;
    const float* __restrict__ bv = dir ? bbv : bfv;

    bf16x8 wfr[4][4];
#pragma unroll
    for (int kt = 0; kt < 4; ++kt)
#pragma unroll
        for (int s = 0; s < 4; ++s) {
            int col = (w + 4 * s) * 16 + lr;
            int k0 = kt * 32 + 4 * lq;
            bf16x8 v;
#pragma unroll
            for (int e = 0; e < 4; ++e) {
                v[e]     = f2bf(Wm[(k0 + e) * G4 + col]);
                v[e + 4] = f2bf(Wm[(k0 + 16 + e) * G4 + col]);
            }
            wfr[kt][s] = v;
        }
    bf16x8 ufr[2][4];
#pragma unroll
    for (int kt = 0; kt < 2; ++kt)
#pragma unroll
        for (int s = 0; s < 4; ++s) {
            int col = (w + 4 * s) * 16 + lr;
            int k0 = kt * 32 + 4 * lq;
            bf16x8 v;
#pragma unroll
            for (int e = 0; e < 4; ++e) {
                v[e]     = f2bf(Um[(k0 + e) * G4 + col]);
                v[e + 4] = f2bf(Um[(k0 + 16 + e) * G4 + col]);
            }
            ufr[kt][s] = v;
        }
    float bsc[4];
#pragma unroll
    for (int s = 0; s < 4; ++s) bsc[s] = bv[(w + 4 * s) * 16 + lr];

    __shared__ __align__(16) char hlds[4096];
    ((f32x4*)hlds)[tid] = (f32x4){0.f, 0.f, 0.f, 0.f};
    __syncthreads();

    const int rd_off = (l * 16) ^ (((l >> 4) & 3) << 4);
    const int j = 16 * w + lr;
    const int kt_j = j >> 5;
    const int elem_j = (j & 3) + 4 * ((j >> 4) & 1);
    int wr_off[4];
#pragma unroll
    for (int e = 0; e < 4; ++e) {
        int fl = 4 * lq + e + 16 * ((j >> 2) & 3);
        wr_off[e] = kt_j * 1024 + ((fl * 16) ^ (((fl >> 4) & 3) << 4)) + elem_j * 2;
    }

    const float* xlane = x + (size_t)(r0 + lr) * (T * F);

    f32x4 xrA[4][2], xrB[4][2];
    { int tt0 = dir ? (T - 1) : 0; LOADX(xrA, tt0); }
    { int tt1 = dir ? (T - 2) : 1; LOADX(xrB, tt1); }

    float c4[4] = {0.f, 0.f, 0.f, 0.f};
    float hq[4] = {0.f, 0.f, 0.f, 0.f};

    for (int t = 0; t < T; t += 2) {
        BODY(t,     xrA, 0, 1);
        BODY(t + 1, xrB, 1, 0);
    }

#pragma unroll
    for (int e = 0; e < 4; ++e) {
        int row = 4 * lq + e;
        hcat[(size_t)(r0 + row) * (2 * H) + dir * H + j] = hq[e];
    }
}

// out[b][e] = relu(sum_k hcat[b][k] * Wd[k][e] + bd[e])   (fp32)
__global__ void dense_kernel(const float* __restrict__ hcat,
                             const float* __restrict__ Wd,
                             const float* __restrict__ bd,
                             float* __restrict__ out) {
    const int b = blockIdx.x;
    const int e = threadIdx.x;   // 128 threads
    float acc = bd[e];
#pragma unroll
    for (int k = 0; k < 2 * H; ++k)
        acc = fmaf(hcat[b * (2 * H) + k], Wd[k * 128 + e], acc);
    out[b * 128 + e] = fmaxf(acc, 0.f);
}

extern "C" void kernel_launch(void* const* d_in, const int* in_sizes, int n_in,
                              void* d_out, int out_size, void* d_ws, size_t ws_size,
                              hipStream_t stream) {
    const float* x       = (const float*)d_in[0];
    const float* W_fwd   = (const float*)d_in[1];
    const float* U_fwd   = (const float*)d_in[2];
    const float* b_fwd   = (const float*)d_in[3];
    const float* W_bwd   = (const float*)d_in[4];
    const float* U_bwd   = (const float*)d_in[5];
    const float* b_bwd   = (const float*)d_in[6];
    const float* W_dense = (const float*)d_in[7];
    const float* b_dense = (const float*)d_in[8];
    float* out = (float*)d_out;

    // xp: 256 tiles x (T/2 pairs) x 4096 B = 256 MB
    const size_t XP_BYTES = (size_t)256 * (T / 2) * 4096;
    const size_t HCAT_BYTES = (size_t)B * 2 * H * 4;

    if (ws_size >= XP_BYTES + HCAT_BYTES) {
        char*  xpb  = (char*)d_ws;
        float* hcat = (float*)((char*)d_ws + XP_BYTES);

        // dual-direction: 32 rowg x 8 tchunks = 256 blocks, one x read
        xw_gemm<<<dim3(32 * TC), dim3(256), 0, stream>>>(
            x, W_fwd, b_fwd, W_bwd, b_bwd, xpb);
        lstm_rec<<<dim3(256), dim3(256), 0, stream>>>(
            xpb, U_fwd, U_bwd, hcat);
        dense_kernel<<<dim3(B), dim3(128), 0, stream>>>(hcat, W_dense, b_dense, out);
    } else {
        float* hcat = (float*)d_ws;
        lstm_mfma<<<dim3(2 * (B / RB)), dim3(256), 0, stream>>>(
            x, W_fwd, U_fwd, b_fwd, W_bwd, U_bwd, b_bwd, hcat);
        dense_kernel<<<dim3(B), dim3(128), 0, stream>>>(hcat, W_dense, b_dense, out);
    }
}